// Round 3
// baseline (19760.489 us; speedup 1.0000x reference)
//
#include <hip/hip_runtime.h>
#include <cstdint>
#include <cstddef>

// PointerDecoder: B=64, L=T=512, E=128, H=256.
// One block per batch runs all 512 steps. Prologue hoists ctx = context@Wc+bc
// and embProj = embed@Wih. Round 3: round-1 chain arithmetic restored VERBATIM
// (pointer chain is tie-sensitive; r1 matched np exactly). Structural-only
// changes: fused gate-reduce+cell, redundant all-thread combines (bit-exact),
// float4 Wq/Wo column-group GEMVs (k-order preserved), emb-row prefetch.

#define DEV static __device__ __forceinline__

DEV float rl(float v, int l) {
    return __int_as_float(__builtin_amdgcn_readlane(__float_as_int(v), l));
}
// ---- round-1 transcendentals, verbatim (chain-critical) ----
DEV float fast_rcp(float d) {
    float r = __builtin_amdgcn_rcpf(d);
    return r * (2.0f - d * r);   // one Newton step -> ~1 ulp
}
DEV float fast_tanh(float x) {
    float e = __expf(fminf(2.0f * x, 88.0f));   // clamp avoids inf*0 NaN in NR
    return 1.0f - 2.0f * fast_rcp(1.0f + e);
}
DEV float fast_sigmoid(float x) {
    float e = __expf(fminf(-x, 88.0f));
    return fast_rcp(1.0f + e);
}

// ---------------- prologue: ctx = context @ Wc + bc  (rows of 256 -> 256) ---
__global__ __launch_bounds__(256) void k_ctx(const float* __restrict__ cin,
                                             const float* __restrict__ Wc,
                                             const float* __restrict__ bc,
                                             float* __restrict__ cout_) {
    __shared__ float rows[8][256];
    const int tid = threadIdx.x, lane = tid & 63;
    const long bl0 = (long)blockIdx.x * 8;
    for (int i = tid; i < 8 * 256; i += 256)
        rows[i >> 8][i & 255] = cin[bl0 * 256 + i];
    __syncthreads();
    float rr[8][4];
#pragma unroll
    for (int r = 0; r < 8; ++r)
#pragma unroll
        for (int q = 0; q < 4; ++q) rr[r][q] = rows[r][q * 64 + lane];
    float acc[8] = {0, 0, 0, 0, 0, 0, 0, 0};
#pragma unroll
    for (int kq = 0; kq < 4; ++kq) {
        for (int kk = 0; kk < 64; ++kk) {
            float wc = Wc[(kq * 64 + kk) * 256 + tid];
#pragma unroll
            for (int r = 0; r < 8; ++r) acc[r] += rl(rr[r][kq], kk) * wc;
        }
    }
    float bcv = bc[tid];
#pragma unroll
    for (int r = 0; r < 8; ++r) cout_[(bl0 + r) * 256 + tid] = acc[r] + bcv;
}

// ------------- prologue: y = x @ Wih  (rows of 128 -> 1024) -----------------
__global__ __launch_bounds__(256) void k_proj(const float* __restrict__ xin,
                                              const float* __restrict__ Wih,
                                              float* __restrict__ yout) {
    __shared__ float rows[8][128];
    const int tid = threadIdx.x, lane = tid & 63;
    const long bl0 = (long)blockIdx.x * 8;
    for (int i = tid; i < 8 * 128; i += 256)
        rows[i >> 7][i & 127] = xin[bl0 * 128 + i];
    __syncthreads();
    float rr[8][2];
#pragma unroll
    for (int r = 0; r < 8; ++r)
#pragma unroll
        for (int q = 0; q < 2; ++q) rr[r][q] = rows[r][q * 64 + lane];
    float4 acc[8];
#pragma unroll
    for (int r = 0; r < 8; ++r) acc[r] = make_float4(0.f, 0.f, 0.f, 0.f);
#pragma unroll
    for (int eq = 0; eq < 2; ++eq) {
        for (int ee = 0; ee < 64; ++ee) {
            const float4 w4 =
                *(const float4*)(Wih + (size_t)(eq * 64 + ee) * 1024 + tid * 4);
#pragma unroll
            for (int r = 0; r < 8; ++r) {
                float xe = rl(rr[r][eq], ee);
                acc[r].x += xe * w4.x; acc[r].y += xe * w4.y;
                acc[r].z += xe * w4.z; acc[r].w += xe * w4.w;
            }
        }
    }
#pragma unroll
    for (int r = 0; r < 8; ++r)
        *(float4*)(yout + (bl0 + r) * 1024 + tid * 4) = acc[r];
}

// ------------- epilogue: out0[b,l,t] = alpha_ws[b,t,l] ------------------
__global__ __launch_bounds__(256) void k_tr(const float* __restrict__ aws,
                                            float* __restrict__ out0) {
    __shared__ float tile[32][33];
    const int b = blockIdx.z, l0 = blockIdx.x * 32, t0 = blockIdx.y * 32;
    const int tx = threadIdx.x, ty = threadIdx.y;
    const float* src = aws + ((size_t)b << 18);
    float* dst = out0 + ((size_t)b << 18);
#pragma unroll
    for (int i = 0; i < 32; i += 8)
        tile[ty + i][tx] = src[(size_t)(t0 + ty + i) * 512 + l0 + tx];
    __syncthreads();
#pragma unroll
    for (int i = 0; i < 32; i += 8)
        dst[(size_t)(l0 + ty + i) * 512 + t0 + tx] = tile[tx][ty + i];
}

// ---------------- main persistent kernel: one block per batch ---------------
__global__ __launch_bounds__(1024) void k_main(
    const float* __restrict__ h0, const float* __restrict__ c0,
    const float* __restrict__ Whh, const float* __restrict__ Wih,
    const float* __restrict__ Wq, const float* __restrict__ Wo,
    const float* __restrict__ bih, const float* __restrict__ bhh,
    const float* __restrict__ bq, const float* __restrict__ bo,
    const float* __restrict__ V, const float* __restrict__ embed,
    const float* __restrict__ dec_in, const float* __restrict__ ctx_ws,
    const float* __restrict__ emb_ws, const float* __restrict__ dec_ws,
    float* __restrict__ alpha_ws, float* __restrict__ out0,
    float* __restrict__ out1, float* __restrict__ out2,
    float* __restrict__ out3, int use_emb, int use_stage) {
    const int b = blockIdx.x;
    const int tid = threadIdx.x;
    const int lane = tid & 63;
    const int w = tid >> 6;     // wave id, 16 waves
    const int tt = tid & 255;
    const int p = tid >> 8;     // 4 k-parts for P1 (wave-uniform)

    __shared__ __align__(16) float h_s[256];
    __shared__ __align__(16) float c_s[256];
    __shared__ __align__(16) float q_s[256];
    __shared__ __align__(16) float ah_s[256];
    __shared__ __align__(16) float bsum_s[1024];
    __shared__ __align__(16) float att_s[512];
    __shared__ __align__(16) float alpha_s[512];
    __shared__ __align__(16) float mask_s[512];
    __shared__ __align__(16) float bq_s[256];
    __shared__ __align__(16) float bo_s[256];
    __shared__ __align__(16) float xp_s[1024];   // projected x row (use_emb)
    __shared__ __align__(16) float x_s[128];     // raw x row (fallback)
    __shared__ __align__(16) float red_s[4096];
    __shared__ float wm_s[8], wS_s[8];
    __shared__ int wi_s[8];

    bsum_s[tid] = bih[tid] + bhh[tid];
    if (tid < 256) {
        h_s[tid] = h0[(b << 8) + tid];
        c_s[tid] = c0[(b << 8) + tid];
        bq_s[tid] = bq[tid];
        bo_s[tid] = bo[tid];
    }
    if (tid < 512) mask_s[tid] = 1.0f;
    if (use_emb) {
        if (tid < 256)
            *(float4*)(xp_s + (tid << 2)) =
                *(const float4*)(dec_ws + ((size_t)b << 10) + (tid << 2));
    } else {
        if (tid < 128) x_s[tid] = dec_in[(b << 7) + tid];
    }
    const float4 V4 = *(const float4*)(V + (lane << 2));
    const float* cbase = ctx_ws + (((size_t)b << 9) << 8);
    __syncthreads();

    for (int t = 0; t < 512; ++t) {
        // ---- P1: partials of h@Whh (+ x@Wih fallback); 4-way k-split ----
        // (round-1 arithmetic: float4 acc, k ascending within quarter)
        {
            float hv = h_s[(p << 6) + lane];
            float4 acc = make_float4(0.f, 0.f, 0.f, 0.f);
            const float* wp = Whh + (size_t)(p << 6) * 1024 + (tt << 2);
#pragma unroll 16
            for (int kk = 0; kk < 64; ++kk) {
                float hk = rl(hv, kk);
                const float4 w4 = *(const float4*)(wp + (size_t)kk * 1024);
                acc.x += hk * w4.x; acc.y += hk * w4.y;
                acc.z += hk * w4.z; acc.w += hk * w4.w;
            }
            if (!use_emb) {
                float xv = x_s[(p << 5) + (lane & 31)];
                const float* wip = Wih + (size_t)(p << 5) * 1024 + (tt << 2);
#pragma unroll 8
                for (int ee = 0; ee < 32; ++ee) {
                    float xe = rl(xv, ee);
                    const float4 w4 = *(const float4*)(wip + (size_t)ee * 1024);
                    acc.x += xe * w4.x; acc.y += xe * w4.y;
                    acc.z += xe * w4.z; acc.w += xe * w4.w;
                }
            }
            *(float4*)(red_s + (p << 10) + (tt << 2)) = acc;
        }
        __syncthreads();                                    // s0
        // ---- B1: gate reduce (round-1 order: p0+p1+p2+p3+bsum, then +er)
        //          fused with LSTM cell. Expressions identical to r1. ----
        if (tid < 256) {
            float gi = red_s[tid] + red_s[1024 + tid] + red_s[2048 + tid] +
                       red_s[3072 + tid] + bsum_s[tid];
            float gf = red_s[256 + tid] + red_s[1280 + tid] +
                       red_s[2304 + tid] + red_s[3328 + tid] +
                       bsum_s[256 + tid];
            float gg = red_s[512 + tid] + red_s[1536 + tid] +
                       red_s[2560 + tid] + red_s[3584 + tid] +
                       bsum_s[512 + tid];
            float go = red_s[768 + tid] + red_s[1792 + tid] +
                       red_s[2816 + tid] + red_s[3840 + tid] +
                       bsum_s[768 + tid];
            if (use_emb) {
                gi += xp_s[tid]; gf += xp_s[256 + tid];
                gg += xp_s[512 + tid]; go += xp_s[768 + tid];
            }
            float ig = fast_sigmoid(gi);
            float fg = fast_sigmoid(gf);
            float ggt = fast_tanh(gg);
            float og = fast_sigmoid(go);
            float cn = fg * c_s[tid] + ig * ggt;
            c_s[tid] = cn;
            h_s[tid] = og * fast_tanh(cn);   // h_t
        }
        __syncthreads();                                    // s1
        // ---- P3: q partials; thread owns 4 cols, 64-k run (r1 k-order) ----
        if (tid < 256) {
            const int u = lane;              // p = wave id = tid>>6
            float hv = h_s[(p ? 0 : 0) + ((tid >> 6) << 6) + u];
            const int pq = tid >> 6;
            float4 acc = make_float4(0.f, 0.f, 0.f, 0.f);
            const float* wp = Wq + (size_t)(pq << 6) * 256 + (u << 2);
#pragma unroll 8
            for (int kk = 0; kk < 64; ++kk) {
                float hk = rl(hv, kk);
                const float4 w4 = *(const float4*)(wp + (size_t)kk * 256);
                acc.x += hk * w4.x; acc.y += hk * w4.y;
                acc.z += hk * w4.z; acc.w += hk * w4.w;
            }
            *(float4*)(red_s + (pq << 8) + (u << 2)) = acc;
        }
        __syncthreads();                                    // s2
        if (tid < 256)
            q_s[tid] = red_s[tid] + red_s[256 + tid] + red_s[512 + tid] +
                       red_s[768 + tid] + bq_s[tid];
        __syncthreads();                                    // s3
        // ---- P4: att[l] = sum_h V[h]*tanh(q[h]+ctx[l,h]); masked -> -1e9 --
        // (round-1 verbatim: expression text + descending butterfly)
        {
            const float4 q4 = *(const float4*)(q_s + (lane << 2));
#pragma unroll 2
            for (int l = w; l < 512; l += 16) {          // one wave per l
                if (mask_s[l] == 0.f) {
                    if (lane == 0) att_s[l] = -1e9f;
                } else {
                    const float4 cc =
                        *(const float4*)(cbase + ((size_t)l << 8) + (lane << 2));
                    float s = V4.x * fast_tanh(q4.x + cc.x) +
                              V4.y * fast_tanh(q4.y + cc.y) +
                              V4.z * fast_tanh(q4.z + cc.z) +
                              V4.w * fast_tanh(q4.w + cc.w);
#pragma unroll
                    for (int off = 32; off > 0; off >>= 1)
                        s += __shfl_xor(s, off, 64);
                    if (lane == 0) att_s[l] = s;
                }
            }
        }
        __syncthreads();                                    // s4
        // ---- P5a: per-wave argmax partials (r1 ascending butterfly) ----
        if (tid < 512) {
            float v = att_s[tid];
            int bi = tid;
#pragma unroll
            for (int off = 1; off < 64; off <<= 1) {
                float ov = __shfl_xor(v, off, 64);
                int oi = __shfl_xor(bi, off, 64);
                if (ov > v || (ov == v && oi < bi)) { v = ov; bi = oi; }
            }
            if (lane == 0) { wm_s[w] = v; wi_s[w] = bi; }
        }
        __syncthreads();                                    // s5
        // ---- P5b: redundant argmax combine (r1 loop, every thread) +
        //           exp partials (r1 descending butterfly) ----
        float e_r = 0.f;
        float m_r; int idx_r;
        {
            m_r = wm_s[0]; idx_r = wi_s[0];
#pragma unroll
            for (int i = 1; i < 8; ++i) {
                float v2 = wm_s[i]; int i2 = wi_s[i];
                if (v2 > m_r || (v2 == m_r && i2 < idx_r)) { m_r = v2; idx_r = i2; }
            }
            if (tid < 512) {
                e_r = __expf(att_s[tid] - m_r);   // masked -> exactly 0
                float ss = e_r;
#pragma unroll
                for (int off = 32; off > 0; off >>= 1)
                    ss += __shfl_xor(ss, off, 64);
                if (lane == 0) wS_s[w] = ss;
            }
        }
        __syncthreads();                                    // s6
        // ---- P5c: redundant S combine (r1 order); alpha; mask; prefetch ---
        {
            float S = 0.f;
#pragma unroll
            for (int i = 0; i < 8; ++i) S += wS_s[i];
            if (tid < 512) {
                float a = e_r / S;              // IEEE div, matches ref
                alpha_s[tid] = a;
                if (use_stage)
                    alpha_ws[((((size_t)b << 9) + t) << 9) + tid] = a;
                else
                    out0[((size_t)b << 18) + ((size_t)tid << 9) + t] = a;
            }
            if (tid == 0) {
                out1[(b << 9) + t] = (float)idx_r;
                mask_s[idx_r] = 0.f;            // for next step
            }
            if (use_emb) {                      // prefetch x@Wih row for t+1
                if (tid < 256)
                    *(float4*)(xp_s + (tid << 2)) = *(const float4*)(
                        emb_ws + ((size_t)((b << 9) + idx_r) << 10) + (tid << 2));
            } else {
                if (tid < 128)
                    x_s[tid] = embed[((size_t)((b << 9) + idx_r) << 7) + tid];
            }
        }
        __syncthreads();                                    // s7
        // ---- P6: attn_h partials (r1 verbatim: l = w mod 16, skip 0) ----
        {
            float ax = 0.f, ay = 0.f, az = 0.f, aw = 0.f;
            const float* cb2 = cbase + (lane << 2);
            for (int l = w; l < 512; l += 16) {
                float al = alpha_s[l];
                if (al != 0.f) {
                    const float4 cc = *(const float4*)(cb2 + ((size_t)l << 8));
                    ax += al * cc.x; ay += al * cc.y;
                    az += al * cc.z; aw += al * cc.w;
                }
            }
            *(float4*)(red_s + (w << 8) + (lane << 2)) =
                make_float4(ax, ay, az, aw);
        }
        __syncthreads();                                    // s8
        if (tid < 256) {
            float s = 0.f;
#pragma unroll
            for (int i = 0; i < 16; ++i) s += red_s[(i << 8) + tid];
            ah_s[tid] = s;
        }
        __syncthreads();                                    // s9
        // ---- P7: h_new partials; thread owns 4 cols, 128-k run (r1 order) -
        if (tid < 256) {
            const int pq = tid >> 6, u = lane;
            const float* src0 = (pq < 2) ? ah_s : h_s;
            float av0 = src0[((pq & 1) << 7) + u];
            float av1 = src0[((pq & 1) << 7) + 64 + u];
            float4 acc = make_float4(0.f, 0.f, 0.f, 0.f);
            const float* wp = Wo + (size_t)(pq << 7) * 256 + (u << 2);
#pragma unroll 8
            for (int kk = 0; kk < 64; ++kk) {
                float hk = rl(av0, kk);
                const float4 w4 = *(const float4*)(wp + (size_t)kk * 256);
                acc.x += hk * w4.x; acc.y += hk * w4.y;
                acc.z += hk * w4.z; acc.w += hk * w4.w;
            }
#pragma unroll 8
            for (int kk = 0; kk < 64; ++kk) {
                float hk = rl(av1, kk);
                const float4 w4 = *(const float4*)(wp + (size_t)(64 + kk) * 256);
                acc.x += hk * w4.x; acc.y += hk * w4.y;
                acc.z += hk * w4.z; acc.w += hk * w4.w;
            }
            *(float4*)(red_s + (pq << 8) + (u << 2)) = acc;
        }
        __syncthreads();                                    // s10
        if (tid < 256)
            h_s[tid] = fast_tanh(red_s[tid] + red_s[256 + tid] +
                                 red_s[512 + tid] + red_s[768 + tid] + bo_s[tid]);
        __syncthreads();                                    // s11
    }
    if (tid < 256) {
        out2[(b << 8) + tid] = h_s[tid];   // h_f
        out3[(b << 8) + tid] = c_s[tid];   // c_f
    }
}

extern "C" void kernel_launch(void* const* d_in, const int* in_sizes, int n_in,
                              void* d_out, int out_size, void* d_ws,
                              size_t ws_size, hipStream_t stream) {
    const float* embed = (const float*)d_in[0];    // (64,512,128)
    const float* dec   = (const float*)d_in[1];    // (64,128)
    const float* h0    = (const float*)d_in[2];    // (64,256)
    const float* c0    = (const float*)d_in[3];    // (64,256)
    const float* ctxin = (const float*)d_in[4];    // (64,512,256)
    const float* Wih   = (const float*)d_in[5];    // (128,1024)
    const float* bih   = (const float*)d_in[6];
    const float* Whh   = (const float*)d_in[7];    // (256,1024)
    const float* bhh   = (const float*)d_in[8];
    const float* Wo    = (const float*)d_in[9];    // (512,256)
    const float* bo    = (const float*)d_in[10];
    const float* Wq    = (const float*)d_in[11];   // (256,256)
    const float* bq    = (const float*)d_in[12];
    const float* Wc    = (const float*)d_in[13];   // (256,256)
    const float* bc    = (const float*)d_in[14];
    const float* V     = (const float*)d_in[15];   // (256,)

    float* out0 = (float*)d_out;            // (64,512,512) alphas
    float* out1 = out0 + 16777216;          // (64,512) pointers (as float)
    float* out2 = out1 + 32768;             // (64,256) h_f
    float* out3 = out2 + 16384;             // (64,256) c_f

    float* ws = (float*)d_ws;
    const size_t wsf = ws_size / 4;
    const size_t SZ_CTX = 8388608, SZ_DEC = 65536, SZ_EMB = 33554432,
                 SZ_AL = 16777216;
    const int use_emb = wsf >= SZ_CTX + SZ_DEC + SZ_EMB;
    const size_t al_off = use_emb ? (SZ_CTX + SZ_DEC + SZ_EMB) : SZ_CTX;
    const int use_stage = wsf >= al_off + SZ_AL;

    float* ws_ctx = ws;
    float* ws_dec = ws + SZ_CTX;
    float* ws_emb = ws + SZ_CTX + SZ_DEC;
    float* ws_al  = ws + al_off;

    k_ctx<<<dim3(4096), dim3(256), 0, stream>>>(ctxin, Wc, bc, ws_ctx);
    if (use_emb) {
        k_proj<<<dim3(4096), dim3(256), 0, stream>>>(embed, Wih, ws_emb);
        k_proj<<<dim3(8), dim3(256), 0, stream>>>(dec, Wih, ws_dec);
    }
    k_main<<<dim3(64), dim3(1024), 0, stream>>>(
        h0, c0, Whh, Wih, Wq, Wo, bih, bhh, bq, bo, V, embed, dec, ws_ctx,
        ws_emb, ws_dec, ws_al, out0, out1, out2, out3, use_emb, use_stage);
    if (use_stage)
        k_tr<<<dim3(16, 16, 64), dim3(32, 8), 0, stream>>>(ws_al, out0);
}

// Round 4
// 15580.147 us; speedup vs baseline: 1.2683x; 1.2683x over previous
//
#include <hip/hip_runtime.h>
#include <cstdint>
#include <cstddef>

// PointerDecoder: B=64, L=T=512, E=128, H=256.
// Round 4: each batch split across 4 blocks (256 blocks total, ~4x CUs).
// All FP chains keep r3's exact associations (r3 passed with pointers exact):
//  - P1 k-quartered into r3's own 4-partial structure; partials exchanged,
//    gate combine + LSTM cell fully redundant per member -> identical h/c.
//  - P4 l-quartered; att values exchanged bitwise -> identical argmax/softmax.
//  - P3/P5/P6 fully redundant; P7 column-quartered (per-column chain verbatim).
// Sync: parity-buffered payloads + monotonic flags, agent-scope atomics.
// Fallback: r3 single-block kernel when ws lacks the comm region.

#define DEV static __device__ __forceinline__

DEV float rl(float v, int l) {
    return __int_as_float(__builtin_amdgcn_readlane(__float_as_int(v), l));
}
// ---- round-1/3 transcendentals, verbatim (chain-critical) ----
DEV float fast_rcp(float d) {
    float r = __builtin_amdgcn_rcpf(d);
    return r * (2.0f - d * r);
}
DEV float fast_tanh(float x) {
    float e = __expf(fminf(2.0f * x, 88.0f));
    return 1.0f - 2.0f * fast_rcp(1.0f + e);
}
DEV float fast_sigmoid(float x) {
    float e = __expf(fminf(-x, 88.0f));
    return fast_rcp(1.0f + e);
}
// ---- agent-scope atomic helpers (cross-XCD safe) ----
DEV void st_rel_u32(uint32_t* p, uint32_t v) {
    __hip_atomic_store(p, v, __ATOMIC_RELEASE, __HIP_MEMORY_SCOPE_AGENT);
}
DEV uint32_t ld_acq_u32(const uint32_t* p) {
    return __hip_atomic_load(p, __ATOMIC_ACQUIRE, __HIP_MEMORY_SCOPE_AGENT);
}
DEV void st_f(float* p, float v) {
    __hip_atomic_store(p, v, __ATOMIC_RELAXED, __HIP_MEMORY_SCOPE_AGENT);
}
DEV float ld_f(const float* p) {
    return __hip_atomic_load(p, __ATOMIC_RELAXED, __HIP_MEMORY_SCOPE_AGENT);
}

// ---------------- prologue: ctx = context @ Wc + bc ------------------------
__global__ __launch_bounds__(256) void k_ctx(const float* __restrict__ cin,
                                             const float* __restrict__ Wc,
                                             const float* __restrict__ bc,
                                             float* __restrict__ cout_) {
    __shared__ float rows[8][256];
    const int tid = threadIdx.x, lane = tid & 63;
    const long bl0 = (long)blockIdx.x * 8;
    for (int i = tid; i < 8 * 256; i += 256)
        rows[i >> 8][i & 255] = cin[bl0 * 256 + i];
    __syncthreads();
    float rr[8][4];
#pragma unroll
    for (int r = 0; r < 8; ++r)
#pragma unroll
        for (int q = 0; q < 4; ++q) rr[r][q] = rows[r][q * 64 + lane];
    float acc[8] = {0, 0, 0, 0, 0, 0, 0, 0};
#pragma unroll
    for (int kq = 0; kq < 4; ++kq) {
        for (int kk = 0; kk < 64; ++kk) {
            float wc = Wc[(kq * 64 + kk) * 256 + tid];
#pragma unroll
            for (int r = 0; r < 8; ++r) acc[r] += rl(rr[r][kq], kk) * wc;
        }
    }
    float bcv = bc[tid];
#pragma unroll
    for (int r = 0; r < 8; ++r) cout_[(bl0 + r) * 256 + tid] = acc[r] + bcv;
}

// ------------- prologue: y = x @ Wih  (rows of 128 -> 1024) -----------------
__global__ __launch_bounds__(256) void k_proj(const float* __restrict__ xin,
                                              const float* __restrict__ Wih,
                                              float* __restrict__ yout) {
    __shared__ float rows[8][128];
    const int tid = threadIdx.x, lane = tid & 63;
    const long bl0 = (long)blockIdx.x * 8;
    for (int i = tid; i < 8 * 128; i += 256)
        rows[i >> 7][i & 127] = xin[bl0 * 128 + i];
    __syncthreads();
    float rr[8][2];
#pragma unroll
    for (int r = 0; r < 8; ++r)
#pragma unroll
        for (int q = 0; q < 2; ++q) rr[r][q] = rows[r][q * 64 + lane];
    float4 acc[8];
#pragma unroll
    for (int r = 0; r < 8; ++r) acc[r] = make_float4(0.f, 0.f, 0.f, 0.f);
#pragma unroll
    for (int eq = 0; eq < 2; ++eq) {
        for (int ee = 0; ee < 64; ++ee) {
            const float4 w4 =
                *(const float4*)(Wih + (size_t)(eq * 64 + ee) * 1024 + tid * 4);
#pragma unroll
            for (int r = 0; r < 8; ++r) {
                float xe = rl(rr[r][eq], ee);
                acc[r].x += xe * w4.x; acc[r].y += xe * w4.y;
                acc[r].z += xe * w4.z; acc[r].w += xe * w4.w;
            }
        }
    }
#pragma unroll
    for (int r = 0; r < 8; ++r)
        *(float4*)(yout + (bl0 + r) * 1024 + tid * 4) = acc[r];
}

// ------------- epilogue: out0[b,l,t] = alpha_ws[b,t,l] ----------------------
__global__ __launch_bounds__(256) void k_tr(const float* __restrict__ aws,
                                            float* __restrict__ out0) {
    __shared__ float tile[32][33];
    const int b = blockIdx.z, l0 = blockIdx.x * 32, t0 = blockIdx.y * 32;
    const int tx = threadIdx.x, ty = threadIdx.y;
    const float* src = aws + ((size_t)b << 18);
    float* dst = out0 + ((size_t)b << 18);
#pragma unroll
    for (int i = 0; i < 32; i += 8)
        tile[ty + i][tx] = src[(size_t)(t0 + ty + i) * 512 + l0 + tx];
    __syncthreads();
#pragma unroll
    for (int i = 0; i < 32; i += 8)
        dst[(size_t)(l0 + ty + i) * 512 + t0 + tx] = tile[tx][ty + i];
}

// ------------- flag zeroing (ws is poisoned before every launch) -----------
__global__ __launch_bounds__(1024) void k_zero(uint32_t* fl) {
    fl[threadIdx.x] = 0u;
    fl[1024 + threadIdx.x] = 0u;
}

// ================= 4-way split main kernel: block = m*64 + g ================
__global__ __launch_bounds__(1024) void k_main4(
    const float* __restrict__ h0, const float* __restrict__ c0,
    const float* __restrict__ Whh, const float* __restrict__ Wq,
    const float* __restrict__ Wo, const float* __restrict__ bih,
    const float* __restrict__ bhh, const float* __restrict__ bq,
    const float* __restrict__ bo, const float* __restrict__ V,
    const float* __restrict__ ctx_ws, const float* __restrict__ emb_ws,
    const float* __restrict__ dec_ws, float* __restrict__ alpha_ws,
    float* __restrict__ out1, float* __restrict__ out2,
    float* __restrict__ out3, float* cg_ws, float* ca_ws, uint32_t* fl_ws) {
    const int g = blockIdx.x & 63;     // batch
    const int q = blockIdx.x >> 6;     // member/quarter 0..3
    const int tid = threadIdx.x;
    const int lane = tid & 63;
    const int w = tid >> 6;            // wave id 0..15

    __shared__ __align__(16) float h_s[256];
    __shared__ __align__(16) float c_s[256];
    __shared__ __align__(16) float q_s[256];
    __shared__ __align__(16) float ah_s[256];
    __shared__ __align__(16) float bsum_s[1024];
    __shared__ __align__(16) float att_s[512];
    __shared__ __align__(16) float alpha_s[512];
    __shared__ __align__(16) float mask_s[512];
    __shared__ __align__(16) float bq_s[256];
    __shared__ __align__(16) float bo_s[256];
    __shared__ __align__(16) float xp_s[1024];
    __shared__ __align__(16) float red_s[4096];
    __shared__ float wm_s[8], wS_s[8];
    __shared__ int wi_s[8];

    bsum_s[tid] = bih[tid] + bhh[tid];
    if (tid < 256) {
        h_s[tid] = h0[(g << 8) + tid];
        c_s[tid] = c0[(g << 8) + tid];
        bq_s[tid] = bq[tid];
        bo_s[tid] = bo[tid];
        *(float4*)(xp_s + (tid << 2)) =
            *(const float4*)(dec_ws + ((size_t)g << 10) + (tid << 2));
    }
    if (tid < 512) mask_s[tid] = 1.0f;
    const float4 V4 = *(const float4*)(V + (lane << 2));
    const float* cbase = ctx_ws + (((size_t)g << 9) << 8);
    __syncthreads();

    for (int t = 0; t < 512; ++t) {
        const int par = t & 1;
        const size_t gq4 = (size_t)(par * 64 + g) * 4;      // comm group base
        float* cgb = cg_ws + (gq4 << 10);                   // gates payloads
        float* cab = ca_ws + (gq4 << 7);                    // att payloads
        uint32_t* fg = fl_ws + par * 256 + (g << 2);        // gates flags
        uint32_t* fa = fl_ws + 512 + par * 256 + (g << 2);  // att flags

        // ---- P1: own k-quarter partial of h@Whh (r3 partial p=q verbatim) -
        if (tid < 256) {
            float hv = h_s[(q << 6) + lane];
            float4 acc = make_float4(0.f, 0.f, 0.f, 0.f);
            const float* wp = Whh + (size_t)(q << 6) * 1024 + (tid << 2);
#pragma unroll 16
            for (int kk = 0; kk < 64; ++kk) {
                float hk = rl(hv, kk);
                const float4 w4 = *(const float4*)(wp + (size_t)kk * 1024);
                acc.x += hk * w4.x; acc.y += hk * w4.y;
                acc.z += hk * w4.z; acc.w += hk * w4.w;
            }
            *(float4*)(red_s + (q << 10) + (tid << 2)) = acc;
        }
        __syncthreads();                                    // b1
        // ---- S_gates publish ----
        st_f(cgb + (q << 10) + tid, red_s[(q << 10) + tid]);
        __syncthreads();                                    // b2 (drain)
        if (tid == 0) st_rel_u32(fg + q, (uint32_t)(t + 1));
        if (tid < 3) {
            const int pm = tid + (tid >= q ? 1 : 0);
            while (ld_acq_u32(fg + pm) < (uint32_t)(t + 1))
                __builtin_amdgcn_s_sleep(1);
        }
        __syncthreads();                                    // b3
#pragma unroll
        for (int jj = 0; jj < 4; ++jj)
            if (jj != q) red_s[(jj << 10) + tid] = ld_f(cgb + (jj << 10) + tid);
        __syncthreads();                                    // b4
        // ---- B1: gate combine + LSTM cell, FULL, r3 verbatim ----
        if (tid < 256) {
            float gi = red_s[tid] + red_s[1024 + tid] + red_s[2048 + tid] +
                       red_s[3072 + tid] + bsum_s[tid];
            float gf = red_s[256 + tid] + red_s[1280 + tid] +
                       red_s[2304 + tid] + red_s[3328 + tid] +
                       bsum_s[256 + tid];
            float gg = red_s[512 + tid] + red_s[1536 + tid] +
                       red_s[2560 + tid] + red_s[3584 + tid] +
                       bsum_s[512 + tid];
            float go = red_s[768 + tid] + red_s[1792 + tid] +
                       red_s[2816 + tid] + red_s[3840 + tid] +
                       bsum_s[768 + tid];
            gi += xp_s[tid]; gf += xp_s[256 + tid];
            gg += xp_s[512 + tid]; go += xp_s[768 + tid];
            float ig = fast_sigmoid(gi);
            float fg2 = fast_sigmoid(gf);
            float ggt = fast_tanh(gg);
            float og = fast_sigmoid(go);
            float cn = fg2 * c_s[tid] + ig * ggt;
            c_s[tid] = cn;
            h_s[tid] = og * fast_tanh(cn);   // h_t (full, identical everywhere)
        }
        __syncthreads();                                    // b5
        // ---- P3: q = h_t @ Wq + bq, FULL redundant, r3 verbatim ----
        if (tid < 256) {
            const int u = lane;
            const int pq = tid >> 6;
            float hv = h_s[(pq << 6) + u];
            float4 acc = make_float4(0.f, 0.f, 0.f, 0.f);
            const float* wp = Wq + (size_t)(pq << 6) * 256 + (u << 2);
#pragma unroll 8
            for (int kk = 0; kk < 64; ++kk) {
                float hk = rl(hv, kk);
                const float4 w4 = *(const float4*)(wp + (size_t)kk * 256);
                acc.x += hk * w4.x; acc.y += hk * w4.y;
                acc.z += hk * w4.z; acc.w += hk * w4.w;
            }
            *(float4*)(red_s + (pq << 8) + (u << 2)) = acc;
        }
        __syncthreads();                                    // b6
        if (tid < 256)
            q_s[tid] = red_s[tid] + red_s[256 + tid] + red_s[512 + tid] +
                       red_s[768 + tid] + bq_s[tid];
        __syncthreads();                                    // b7
        // ---- P4: scores for own l-quarter (per-l body r3 verbatim) ----
        {
            const float4 q4 = *(const float4*)(q_s + (lane << 2));
#pragma unroll 2
            for (int i = 0; i < 8; ++i) {
                const int l = (q << 7) + (i << 4) + w;
                if (mask_s[l] == 0.f) {
                    if (lane == 0) att_s[l] = -1e9f;
                } else {
                    const float4 cc =
                        *(const float4*)(cbase + ((size_t)l << 8) + (lane << 2));
                    float s = V4.x * fast_tanh(q4.x + cc.x) +
                              V4.y * fast_tanh(q4.y + cc.y) +
                              V4.z * fast_tanh(q4.z + cc.z) +
                              V4.w * fast_tanh(q4.w + cc.w);
#pragma unroll
                    for (int off = 32; off > 0; off >>= 1)
                        s += __shfl_xor(s, off, 64);
                    if (lane == 0) att_s[l] = s;
                }
            }
        }
        __syncthreads();                                    // b8
        // ---- S_att publish/exchange (bitwise) ----
        if (tid < 128) st_f(cab + (q << 7) + tid, att_s[(q << 7) + tid]);
        __syncthreads();                                    // b9 (drain)
        if (tid == 0) st_rel_u32(fa + q, (uint32_t)(t + 1));
        if (tid < 3) {
            const int pm = tid + (tid >= q ? 1 : 0);
            while (ld_acq_u32(fa + pm) < (uint32_t)(t + 1))
                __builtin_amdgcn_s_sleep(1);
        }
        __syncthreads();                                    // b10
        if (tid < 384) {
            const int rel = tid >> 7;
            const int pm = rel + (rel >= q ? 1 : 0);
            const int word = tid & 127;
            att_s[(pm << 7) + word] = ld_f(cab + (pm << 7) + word);
        }
        __syncthreads();                                    // b11
        // ---- P5a: per-wave argmax partials (r3 verbatim) ----
        if (tid < 512) {
            float v = att_s[tid];
            int bi = tid;
#pragma unroll
            for (int off = 1; off < 64; off <<= 1) {
                float ov = __shfl_xor(v, off, 64);
                int oi = __shfl_xor(bi, off, 64);
                if (ov > v || (ov == v && oi < bi)) { v = ov; bi = oi; }
            }
            if (lane == 0) { wm_s[w] = v; wi_s[w] = bi; }
        }
        __syncthreads();                                    // b12
        // ---- P5b: redundant argmax combine + exp partials (r3 verbatim) ---
        float e_r = 0.f;
        float m_r; int idx_r;
        {
            m_r = wm_s[0]; idx_r = wi_s[0];
#pragma unroll
            for (int i = 1; i < 8; ++i) {
                float v2 = wm_s[i]; int i2 = wi_s[i];
                if (v2 > m_r || (v2 == m_r && i2 < idx_r)) { m_r = v2; idx_r = i2; }
            }
            if (tid < 512) {
                e_r = __expf(att_s[tid] - m_r);
                float ss = e_r;
#pragma unroll
                for (int off = 32; off > 0; off >>= 1)
                    ss += __shfl_xor(ss, off, 64);
                if (lane == 0) wS_s[w] = ss;
            }
        }
        __syncthreads();                                    // b13
        // ---- P5c: S combine; alpha (write own quarter); mask; prefetch ----
        {
            float S = 0.f;
#pragma unroll
            for (int i = 0; i < 8; ++i) S += wS_s[i];
            if (tid < 512) {
                float a = e_r / S;
                alpha_s[tid] = a;
                if ((tid >> 7) == q)
                    alpha_ws[((((size_t)g << 9) + t) << 9) + tid] = a;
            }
            if (q == 0 && tid == 0) out1[(g << 9) + t] = (float)idx_r;
            if (tid == 0) mask_s[idx_r] = 0.f;
            if (tid < 256)
                *(float4*)(xp_s + (tid << 2)) = *(const float4*)(
                    emb_ws + ((size_t)((g << 9) + idx_r) << 10) + (tid << 2));
        }
        __syncthreads();                                    // b14
        // ---- P6: attn_h FULL redundant (r3 verbatim) ----
        {
            float ax = 0.f, ay = 0.f, az = 0.f, aw = 0.f;
            const float* cb2 = cbase + (lane << 2);
            for (int l = w; l < 512; l += 16) {
                float al = alpha_s[l];
                if (al != 0.f) {
                    const float4 cc = *(const float4*)(cb2 + ((size_t)l << 8));
                    ax += al * cc.x; ay += al * cc.y;
                    az += al * cc.z; aw += al * cc.w;
                }
            }
            *(float4*)(red_s + (w << 8) + (lane << 2)) =
                make_float4(ax, ay, az, aw);
        }
        __syncthreads();                                    // b15
        if (tid < 256) {
            float s = 0.f;
#pragma unroll
            for (int i = 0; i < 16; ++i) s += red_s[(i << 8) + tid];
            ah_s[tid] = s;
        }
        __syncthreads();                                    // b16
        // ---- P7: h_new own column-quarter (per-column chain r3-exact) ----
        if (tid < 256) {
            const int pq = tid >> 6;
            const float* src0 = (pq < 2) ? ah_s : h_s;
            float av0 = src0[((pq & 1) << 7) + lane];
            float av1 = src0[((pq & 1) << 7) + 64 + lane];
            const int c = (q << 6) + lane;
            float acc = 0.f;
            const float* wp = Wo + (size_t)(pq << 7) * 256 + c;
#pragma unroll 8
            for (int kk = 0; kk < 64; ++kk)
                acc += rl(av0, kk) * wp[(size_t)kk * 256];
#pragma unroll 8
            for (int kk = 0; kk < 64; ++kk)
                acc += rl(av1, kk) * wp[(size_t)(64 + kk) * 256];
            red_s[(pq << 6) + lane] = acc;
        }
        __syncthreads();                                    // b17
        if (tid < 64)
            h_s[(q << 6) + tid] =
                fast_tanh(red_s[tid] + red_s[64 + tid] + red_s[128 + tid] +
                          red_s[192 + tid] + bo_s[(q << 6) + tid]);
        __syncthreads();                                    // b18
    }
    if (tid < 64) out2[(g << 8) + (q << 6) + tid] = h_s[(q << 6) + tid];
    if (q == 0 && tid < 256) out3[(g << 8) + tid] = c_s[tid];
}

// ================= fallback: r3 single-block kernel (verbatim) ==============
__global__ __launch_bounds__(1024) void k_main1(
    const float* __restrict__ h0, const float* __restrict__ c0,
    const float* __restrict__ Whh, const float* __restrict__ Wih,
    const float* __restrict__ Wq, const float* __restrict__ Wo,
    const float* __restrict__ bih, const float* __restrict__ bhh,
    const float* __restrict__ bq, const float* __restrict__ bo,
    const float* __restrict__ V, const float* __restrict__ embed,
    const float* __restrict__ dec_in, const float* __restrict__ ctx_ws,
    const float* __restrict__ emb_ws, const float* __restrict__ dec_ws,
    float* __restrict__ alpha_ws, float* __restrict__ out0,
    float* __restrict__ out1, float* __restrict__ out2,
    float* __restrict__ out3, int use_emb, int use_stage) {
    const int b = blockIdx.x;
    const int tid = threadIdx.x;
    const int lane = tid & 63;
    const int w = tid >> 6;
    const int tt = tid & 255;
    const int p = tid >> 8;

    __shared__ __align__(16) float h_s[256];
    __shared__ __align__(16) float c_s[256];
    __shared__ __align__(16) float q_s[256];
    __shared__ __align__(16) float ah_s[256];
    __shared__ __align__(16) float bsum_s[1024];
    __shared__ __align__(16) float att_s[512];
    __shared__ __align__(16) float alpha_s[512];
    __shared__ __align__(16) float mask_s[512];
    __shared__ __align__(16) float bq_s[256];
    __shared__ __align__(16) float bo_s[256];
    __shared__ __align__(16) float xp_s[1024];
    __shared__ __align__(16) float x_s[128];
    __shared__ __align__(16) float red_s[4096];
    __shared__ float wm_s[8], wS_s[8];
    __shared__ int wi_s[8];

    bsum_s[tid] = bih[tid] + bhh[tid];
    if (tid < 256) {
        h_s[tid] = h0[(b << 8) + tid];
        c_s[tid] = c0[(b << 8) + tid];
        bq_s[tid] = bq[tid];
        bo_s[tid] = bo[tid];
    }
    if (tid < 512) mask_s[tid] = 1.0f;
    if (use_emb) {
        if (tid < 256)
            *(float4*)(xp_s + (tid << 2)) =
                *(const float4*)(dec_ws + ((size_t)b << 10) + (tid << 2));
    } else {
        if (tid < 128) x_s[tid] = dec_in[(b << 7) + tid];
    }
    const float4 V4 = *(const float4*)(V + (lane << 2));
    const float* cbase = ctx_ws + (((size_t)b << 9) << 8);
    __syncthreads();

    for (int t = 0; t < 512; ++t) {
        {
            float hv = h_s[(p << 6) + lane];
            float4 acc = make_float4(0.f, 0.f, 0.f, 0.f);
            const float* wp = Whh + (size_t)(p << 6) * 1024 + (tt << 2);
#pragma unroll 16
            for (int kk = 0; kk < 64; ++kk) {
                float hk = rl(hv, kk);
                const float4 w4 = *(const float4*)(wp + (size_t)kk * 1024);
                acc.x += hk * w4.x; acc.y += hk * w4.y;
                acc.z += hk * w4.z; acc.w += hk * w4.w;
            }
            if (!use_emb) {
                float xv = x_s[(p << 5) + (lane & 31)];
                const float* wip = Wih + (size_t)(p << 5) * 1024 + (tt << 2);
#pragma unroll 8
                for (int ee = 0; ee < 32; ++ee) {
                    float xe = rl(xv, ee);
                    const float4 w4 = *(const float4*)(wip + (size_t)ee * 1024);
                    acc.x += xe * w4.x; acc.y += xe * w4.y;
                    acc.z += xe * w4.z; acc.w += xe * w4.w;
                }
            }
            *(float4*)(red_s + (p << 10) + (tt << 2)) = acc;
        }
        __syncthreads();
        if (tid < 256) {
            float gi = red_s[tid] + red_s[1024 + tid] + red_s[2048 + tid] +
                       red_s[3072 + tid] + bsum_s[tid];
            float gf = red_s[256 + tid] + red_s[1280 + tid] +
                       red_s[2304 + tid] + red_s[3328 + tid] +
                       bsum_s[256 + tid];
            float gg = red_s[512 + tid] + red_s[1536 + tid] +
                       red_s[2560 + tid] + red_s[3584 + tid] +
                       bsum_s[512 + tid];
            float go = red_s[768 + tid] + red_s[1792 + tid] +
                       red_s[2816 + tid] + red_s[3840 + tid] +
                       bsum_s[768 + tid];
            if (use_emb) {
                gi += xp_s[tid]; gf += xp_s[256 + tid];
                gg += xp_s[512 + tid]; go += xp_s[768 + tid];
            }
            float ig = fast_sigmoid(gi);
            float fg = fast_sigmoid(gf);
            float ggt = fast_tanh(gg);
            float og = fast_sigmoid(go);
            float cn = fg * c_s[tid] + ig * ggt;
            c_s[tid] = cn;
            h_s[tid] = og * fast_tanh(cn);
        }
        __syncthreads();
        if (tid < 256) {
            const int u = lane;
            const int pq = tid >> 6;
            float hv = h_s[(pq << 6) + u];
            float4 acc = make_float4(0.f, 0.f, 0.f, 0.f);
            const float* wp = Wq + (size_t)(pq << 6) * 256 + (u << 2);
#pragma unroll 8
            for (int kk = 0; kk < 64; ++kk) {
                float hk = rl(hv, kk);
                const float4 w4 = *(const float4*)(wp + (size_t)kk * 256);
                acc.x += hk * w4.x; acc.y += hk * w4.y;
                acc.z += hk * w4.z; acc.w += hk * w4.w;
            }
            *(float4*)(red_s + (pq << 8) + (u << 2)) = acc;
        }
        __syncthreads();
        if (tid < 256)
            q_s[tid] = red_s[tid] + red_s[256 + tid] + red_s[512 + tid] +
                       red_s[768 + tid] + bq_s[tid];
        __syncthreads();
        {
            const float4 q4 = *(const float4*)(q_s + (lane << 2));
#pragma unroll 2
            for (int l = w; l < 512; l += 16) {
                if (mask_s[l] == 0.f) {
                    if (lane == 0) att_s[l] = -1e9f;
                } else {
                    const float4 cc =
                        *(const float4*)(cbase + ((size_t)l << 8) + (lane << 2));
                    float s = V4.x * fast_tanh(q4.x + cc.x) +
                              V4.y * fast_tanh(q4.y + cc.y) +
                              V4.z * fast_tanh(q4.z + cc.z) +
                              V4.w * fast_tanh(q4.w + cc.w);
#pragma unroll
                    for (int off = 32; off > 0; off >>= 1)
                        s += __shfl_xor(s, off, 64);
                    if (lane == 0) att_s[l] = s;
                }
            }
        }
        __syncthreads();
        if (tid < 512) {
            float v = att_s[tid];
            int bi = tid;
#pragma unroll
            for (int off = 1; off < 64; off <<= 1) {
                float ov = __shfl_xor(v, off, 64);
                int oi = __shfl_xor(bi, off, 64);
                if (ov > v || (ov == v && oi < bi)) { v = ov; bi = oi; }
            }
            if (lane == 0) { wm_s[w] = v; wi_s[w] = bi; }
        }
        __syncthreads();
        float e_r = 0.f;
        float m_r; int idx_r;
        {
            m_r = wm_s[0]; idx_r = wi_s[0];
#pragma unroll
            for (int i = 1; i < 8; ++i) {
                float v2 = wm_s[i]; int i2 = wi_s[i];
                if (v2 > m_r || (v2 == m_r && i2 < idx_r)) { m_r = v2; idx_r = i2; }
            }
            if (tid < 512) {
                e_r = __expf(att_s[tid] - m_r);
                float ss = e_r;
#pragma unroll
                for (int off = 32; off > 0; off >>= 1)
                    ss += __shfl_xor(ss, off, 64);
                if (lane == 0) wS_s[w] = ss;
            }
        }
        __syncthreads();
        {
            float S = 0.f;
#pragma unroll
            for (int i = 0; i < 8; ++i) S += wS_s[i];
            if (tid < 512) {
                float a = e_r / S;
                alpha_s[tid] = a;
                if (use_stage)
                    alpha_ws[((((size_t)b << 9) + t) << 9) + tid] = a;
                else
                    out0[((size_t)b << 18) + ((size_t)tid << 9) + t] = a;
            }
            if (tid == 0) {
                out1[(b << 9) + t] = (float)idx_r;
                mask_s[idx_r] = 0.f;
            }
            if (use_emb) {
                if (tid < 256)
                    *(float4*)(xp_s + (tid << 2)) = *(const float4*)(
                        emb_ws + ((size_t)((b << 9) + idx_r) << 10) + (tid << 2));
            } else {
                if (tid < 128)
                    x_s[tid] = embed[((size_t)((b << 9) + idx_r) << 7) + tid];
            }
        }
        __syncthreads();
        {
            float ax = 0.f, ay = 0.f, az = 0.f, aw = 0.f;
            const float* cb2 = cbase + (lane << 2);
            for (int l = w; l < 512; l += 16) {
                float al = alpha_s[l];
                if (al != 0.f) {
                    const float4 cc = *(const float4*)(cb2 + ((size_t)l << 8));
                    ax += al * cc.x; ay += al * cc.y;
                    az += al * cc.z; aw += al * cc.w;
                }
            }
            *(float4*)(red_s + (w << 8) + (lane << 2)) =
                make_float4(ax, ay, az, aw);
        }
        __syncthreads();
        if (tid < 256) {
            float s = 0.f;
#pragma unroll
            for (int i = 0; i < 16; ++i) s += red_s[(i << 8) + tid];
            ah_s[tid] = s;
        }
        __syncthreads();
        if (tid < 256) {
            const int pq = tid >> 6, u = lane;
            const float* src0 = (pq < 2) ? ah_s : h_s;
            float av0 = src0[((pq & 1) << 7) + u];
            float av1 = src0[((pq & 1) << 7) + 64 + u];
            float4 acc = make_float4(0.f, 0.f, 0.f, 0.f);
            const float* wp = Wo + (size_t)(pq << 7) * 256 + (u << 2);
#pragma unroll 8
            for (int kk = 0; kk < 64; ++kk) {
                float hk = rl(av0, kk);
                const float4 w4 = *(const float4*)(wp + (size_t)kk * 256);
                acc.x += hk * w4.x; acc.y += hk * w4.y;
                acc.z += hk * w4.z; acc.w += hk * w4.w;
            }
#pragma unroll 8
            for (int kk = 0; kk < 64; ++kk) {
                float hk = rl(av1, kk);
                const float4 w4 = *(const float4*)(wp + (size_t)(64 + kk) * 256);
                acc.x += hk * w4.x; acc.y += hk * w4.y;
                acc.z += hk * w4.z; acc.w += hk * w4.w;
            }
            *(float4*)(red_s + (pq << 8) + (u << 2)) = acc;
        }
        __syncthreads();
        if (tid < 256)
            h_s[tid] = fast_tanh(red_s[tid] + red_s[256 + tid] +
                                 red_s[512 + tid] + red_s[768 + tid] + bo_s[tid]);
        __syncthreads();
    }
    if (tid < 256) {
        out2[(b << 8) + tid] = h_s[tid];
        out3[(b << 8) + tid] = c_s[tid];
    }
}

extern "C" void kernel_launch(void* const* d_in, const int* in_sizes, int n_in,
                              void* d_out, int out_size, void* d_ws,
                              size_t ws_size, hipStream_t stream) {
    const float* embed = (const float*)d_in[0];
    const float* dec   = (const float*)d_in[1];
    const float* h0    = (const float*)d_in[2];
    const float* c0    = (const float*)d_in[3];
    const float* ctxin = (const float*)d_in[4];
    const float* Wih   = (const float*)d_in[5];
    const float* bih   = (const float*)d_in[6];
    const float* Whh   = (const float*)d_in[7];
    const float* bhh   = (const float*)d_in[8];
    const float* Wo    = (const float*)d_in[9];
    const float* bo    = (const float*)d_in[10];
    const float* Wq    = (const float*)d_in[11];
    const float* bq    = (const float*)d_in[12];
    const float* Wc    = (const float*)d_in[13];
    const float* bc    = (const float*)d_in[14];
    const float* V     = (const float*)d_in[15];

    float* out0 = (float*)d_out;            // (64,512,512) alphas
    float* out1 = out0 + 16777216;          // (64,512) pointers
    float* out2 = out1 + 32768;             // (64,256) h_f
    float* out3 = out2 + 16384;             // (64,256) c_f

    float* ws = (float*)d_ws;
    const size_t wsf = ws_size / 4;
    const size_t SZ_CTX = 8388608, SZ_DEC = 65536, SZ_EMB = 33554432,
                 SZ_AL = 16777216;
    const size_t SZ_CG = 2ull * 64 * 4 * 1024;   // 524288
    const size_t SZ_CA = 2ull * 64 * 4 * 128;    // 65536
    const size_t SZ_FL = 4096;                   // flag area (floats worth)
    const int use_emb = wsf >= SZ_CTX + SZ_DEC + SZ_EMB;
    const size_t al_off = use_emb ? (SZ_CTX + SZ_DEC + SZ_EMB) : SZ_CTX;
    const int use_stage = wsf >= al_off + SZ_AL;
    const size_t comm_off = al_off + SZ_AL;
    const int use_split =
        use_emb && use_stage && (wsf >= comm_off + SZ_CG + SZ_CA + SZ_FL);

    float* ws_ctx = ws;
    float* ws_dec = ws + SZ_CTX;
    float* ws_emb = ws + SZ_CTX + SZ_DEC;
    float* ws_al  = ws + al_off;
    float* ws_cg  = ws + comm_off;
    float* ws_ca  = ws_cg + SZ_CG;
    uint32_t* ws_fl = (uint32_t*)(ws_ca + SZ_CA);

    k_ctx<<<dim3(4096), dim3(256), 0, stream>>>(ctxin, Wc, bc, ws_ctx);
    if (use_emb) {
        k_proj<<<dim3(4096), dim3(256), 0, stream>>>(embed, Wih, ws_emb);
        k_proj<<<dim3(8), dim3(256), 0, stream>>>(dec, Wih, ws_dec);
    }
    if (use_split) {
        k_zero<<<dim3(1), dim3(1024), 0, stream>>>(ws_fl);
        k_main4<<<dim3(256), dim3(1024), 0, stream>>>(
            h0, c0, Whh, Wq, Wo, bih, bhh, bq, bo, V, ws_ctx, ws_emb, ws_dec,
            ws_al, out1, out2, out3, ws_cg, ws_ca, ws_fl);
    } else {
        k_main1<<<dim3(64), dim3(1024), 0, stream>>>(
            h0, c0, Whh, Wih, Wq, Wo, bih, bhh, bq, bo, V, embed, dec, ws_ctx,
            ws_emb, ws_dec, ws_al, out0, out1, out2, out3, use_emb, use_stage);
    }
    if (use_stage)
        k_tr<<<dim3(16, 16, 64), dim3(32, 8), 0, stream>>>(ws_al, out0);
}